// Round 2
// baseline (136.866 us; speedup 1.0000x reference)
//
#include <hip/hip_runtime.h>
#include <math.h>

#define NATOMS   4096
#define NRBF     16
#define NHID     64
#define CUTOFF2  25.0f
// ETA = 0.5*(5.0-0.5)/16 = 0.140625 ; 1/(2*ETA^2)
#define INV_2ETA2 25.283950617283951f
#define PI_OVER_CUTOFF 0.62831853071795865f  // pi / 5
#define CAP      128   // neighbor-list capacity per atom (mean ~33, 128 is >10 sigma)

// 1 block = 4 atoms (1 per wave). All 4096 positions staged in LDS.
// Sieve (cheap, all pairs) -> per-wave compact neighbor list -> dense RBF
// on <=2 wave-iters -> per-wave 16->64->64->1 MLP -> one atomicAdd per wave.
__global__ __launch_bounds__(256) void short_range_kernel(
    const float* __restrict__ pos,
    const float* __restrict__ centers,
    const float* __restrict__ W1, const float* __restrict__ b1,
    const float* __restrict__ W2, const float* __restrict__ b2,
    const float* __restrict__ W3, const float* __restrict__ b3,
    float* __restrict__ out)
{
    __shared__ float spos[NATOMS * 3];   // 48 KB, AoS copy of positions
    __shared__ float sdist[4][CAP];      // 2 KB, per-wave compacted distances
    __shared__ float s_h1[4][NHID];      // 1 KB, per-wave hidden activations
    __shared__ int   scount[4];

    const int tid  = threadIdx.x;
    const int lane = tid & 63;
    const int wave = tid >> 6;
    const int i    = blockIdx.x * 4 + wave;   // this wave's atom

    if (tid < 4) scount[tid] = 0;

    // ---- stage all positions into LDS (12288 floats = 3072 float4) ----
    const float4* p4 = (const float4*)pos;
    float4* s4 = (float4*)spos;
#pragma unroll
    for (int t = 0; t < 12; ++t) s4[tid + 256 * t] = p4[tid + 256 * t];
    __syncthreads();

    const float xi = spos[3 * i + 0];
    const float yi = spos[3 * i + 1];
    const float zi = spos[3 * i + 2];

    // ---- sieve: all j from LDS, compact passing distances ----
    for (int j = lane; j < NATOMS; j += 64) {
        const float dx = spos[3 * j + 0] - xi;
        const float dy = spos[3 * j + 1] - yi;
        const float dz = spos[3 * j + 2] - zi;
        const float sq = dx * dx + dy * dy + dz * dz;
        if (sq > 0.0f && sq < CUTOFF2) {
            const int slot = atomicAdd(&scount[wave], 1);
            if (slot < CAP) sdist[wave][slot] = sqrtf(sq);
        }
    }
    __syncthreads();

    // ---- dense RBF expansion over the compacted list ----
    float c[NRBF];
#pragma unroll
    for (int k = 0; k < NRBF; ++k) c[k] = centers[k];

    const int count = min(scount[wave], CAP);
    float facc[NRBF];
#pragma unroll
    for (int k = 0; k < NRBF; ++k) facc[k] = 0.0f;

    for (int e = lane; e < count; e += 64) {
        const float d = sdist[wave][e];
        const float w = 0.5f * (1.0f + __cosf(d * PI_OVER_CUTOFF));
#pragma unroll
        for (int k = 0; k < NRBF; ++k) {
            const float t = d - c[k];
            facc[k] += w * __expf(-(t * t) * INV_2ETA2);
        }
    }
    // butterfly: afterwards every lane holds the full feature sums
#pragma unroll
    for (int k = 0; k < NRBF; ++k) {
        float v = facc[k];
#pragma unroll
        for (int off = 32; off > 0; off >>= 1) v += __shfl_xor(v, off, 64);
        facc[k] = v;
    }

    // ---- MLP: lane n owns hidden unit n (NHID == wavefront size == 64) ----
    float h = b1[lane];
#pragma unroll
    for (int k = 0; k < NRBF; ++k) h += facc[k] * W1[k * NHID + lane];
    h = h / (1.0f + __expf(-h));         // silu
    s_h1[wave][lane] = h;
    __syncthreads();

    float h2 = b2[lane];
#pragma unroll 8
    for (int m = 0; m < NHID; ++m) h2 += s_h1[wave][m] * W2[m * NHID + lane];
    h2 = h2 / (1.0f + __expf(-h2));      // silu
    float e = h2 * W3[lane];
#pragma unroll
    for (int off = 32; off > 0; off >>= 1) e += __shfl_xor(e, off, 64);
    if (lane == 0) atomicAdd(out, e + b3[0]);
}

extern "C" void kernel_launch(void* const* d_in, const int* in_sizes, int n_in,
                              void* d_out, int out_size, void* d_ws, size_t ws_size,
                              hipStream_t stream) {
    const float* pos     = (const float*)d_in[0];
    const float* centers = (const float*)d_in[1];
    const float* W1      = (const float*)d_in[2];
    const float* b1      = (const float*)d_in[3];
    const float* W2      = (const float*)d_in[4];
    const float* b2      = (const float*)d_in[5];
    const float* W3      = (const float*)d_in[6];
    const float* b3      = (const float*)d_in[7];
    float* out = (float*)d_out;

    // d_out is poisoned to 0xAA before every replay; zero it (capture-safe)
    hipMemsetAsync(out, 0, sizeof(float), stream);

    hipLaunchKernelGGL(short_range_kernel, dim3(NATOMS / 4), dim3(256), 0, stream,
                       pos, centers, W1, b1, W2, b2, W3, b3, out);
}

// Round 3
// 128.118 us; speedup vs baseline: 1.0683x; 1.0683x over previous
//
#include <hip/hip_runtime.h>
#include <math.h>

#define NATOMS   4096
#define NRBF     16
#define NHID     64
#define CUTOFF2  25.0f
// ETA = 0.5*(5.0-0.5)/16 = 0.140625 ; 1/(2*ETA^2)
#define INV_2ETA2 25.283950617283951f
#define PI_OVER_CUTOFF 0.62831853071795865f  // pi / 5
#define CAP      64   // per-wave neighbor capacity (mean ~8, Poisson tail << 1e-20)

// Block per atom, 4 waves split the 4096-j range (1024 each).
// Sieve: coalesced-ish AoS global reads (L1/L2-resident), branch-free
// ballot+prefix compaction into a tiny per-wave LDS distance list.
// Dense RBF: lane -> (entry, feature) transposed mapping, 1 exp/lane.
// MLP on wave 0 only; one atomicAdd per block.
__global__ __launch_bounds__(256) void short_range_kernel(
    const float* __restrict__ pos,
    const float* __restrict__ centers,
    const float* __restrict__ W1, const float* __restrict__ b1,
    const float* __restrict__ W2, const float* __restrict__ b2,
    const float* __restrict__ W3, const float* __restrict__ b3,
    float* __restrict__ out)
{
    __shared__ float sdist[4][CAP];    // 1 KB
    __shared__ float s_part[4][NRBF];  // 256 B
    __shared__ float s_feat[NRBF];
    __shared__ float s_h1[NHID];

    const int tid  = threadIdx.x;
    const int lane = tid & 63;
    const int wave = tid >> 6;
    const int i    = blockIdx.x;

    const float xi = pos[3 * i + 0];
    const float yi = pos[3 * i + 1];
    const float zi = pos[3 * i + 2];

    // ---- sieve: 16 unrolled iters, ballot-compact passing distances ----
    int base = 0;
    const int j0 = wave * 1024 + lane;
#pragma unroll
    for (int it = 0; it < 16; ++it) {
        const int j = j0 + it * 64;
        const float dx = pos[3 * j + 0] - xi;
        const float dy = pos[3 * j + 1] - yi;
        const float dz = pos[3 * j + 2] - zi;
        const float sq = dx * dx + dy * dy + dz * dz;
        const bool pass = (sq > 0.0f) && (sq < CUTOFF2);
        const unsigned long long mask = __ballot(pass);
        if (pass) {
            const int slot = base + (int)__popcll(mask & ((1ull << lane) - 1ull));
            if (slot < CAP) sdist[wave][slot] = sqrtf(sq);
        }
        base += (int)__popcll(mask);
    }
    const int count = min(base, CAP);

    // ---- dense RBF, transposed: entry e = e0 + (lane>>4), feature = lane&15 ----
    const int   kf   = lane & 15;
    const int   eoff = lane >> 4;
    const float ck   = centers[kf];
    float acc = 0.0f;
    for (int e0 = 0; e0 < count; e0 += 4) {
        const int e = e0 + eoff;
        if (e < count) {
            const float d = sdist[wave][e];
            const float w = 0.5f * (1.0f + __cosf(d * PI_OVER_CUTOFF));
            const float t = d - ck;
            acc += w * __expf(-(t * t) * INV_2ETA2);
        }
    }
    // fold the 4 entry-groups: lanes 0..15 end with full per-feature sums
    acc += __shfl_xor(acc, 16, 64);
    acc += __shfl_xor(acc, 32, 64);
    if (lane < NRBF) s_part[wave][lane] = acc;
    __syncthreads();

    // ---- MLP epilogue, wave 0 only (no further barriers: waves 1-3 exit) ----
    if (wave == 0) {
        if (lane < NRBF)
            s_feat[lane] = s_part[0][lane] + s_part[1][lane]
                         + s_part[2][lane] + s_part[3][lane];
        // single-wave LDS ops are in program order: no barrier needed
        float h = b1[lane];
#pragma unroll
        for (int k = 0; k < NRBF; ++k) h += s_feat[k] * W1[k * NHID + lane];
        h = h / (1.0f + __expf(-h));   // silu
        s_h1[lane] = h;
        float h2 = b2[lane];
#pragma unroll 8
        for (int m = 0; m < NHID; ++m) h2 += s_h1[m] * W2[m * NHID + lane];
        h2 = h2 / (1.0f + __expf(-h2)); // silu
        float e = h2 * W3[lane];
#pragma unroll
        for (int off = 32; off > 0; off >>= 1) e += __shfl_xor(e, off, 64);
        if (lane == 0) atomicAdd(out, e + b3[0]);
    }
}

extern "C" void kernel_launch(void* const* d_in, const int* in_sizes, int n_in,
                              void* d_out, int out_size, void* d_ws, size_t ws_size,
                              hipStream_t stream) {
    const float* pos     = (const float*)d_in[0];
    const float* centers = (const float*)d_in[1];
    const float* W1      = (const float*)d_in[2];
    const float* b1      = (const float*)d_in[3];
    const float* W2      = (const float*)d_in[4];
    const float* b2      = (const float*)d_in[5];
    const float* W3      = (const float*)d_in[6];
    const float* b3      = (const float*)d_in[7];
    float* out = (float*)d_out;

    // d_out is poisoned to 0xAA before every replay; zero it (capture-safe)
    hipMemsetAsync(out, 0, sizeof(float), stream);

    hipLaunchKernelGGL(short_range_kernel, dim3(NATOMS), dim3(256), 0, stream,
                       pos, centers, W1, b1, W2, b2, W3, b3, out);
}